// Round 1
// 672.183 us; speedup vs baseline: 1.4379x; 1.4379x over previous
//
#include <hip/hip_runtime.h>
#include <hip/hip_bf16.h>

typedef __hip_bfloat16 bf16;
typedef __attribute__((ext_vector_type(8))) short s8v;   // 8 bf16 = 16 B
typedef __attribute__((ext_vector_type(4))) short s4v;   // 4 bf16 = 8 B
typedef __attribute__((ext_vector_type(4))) float f4v;   // MFMA C/D frag

#define B_  4
#define L_  2048
#define D_  2048
#define H_  16
#define HD_ 128

// ---------------------------------------------------------------------------
// dtype helpers (m: 0 = bf16, 1 = fp32) — only used on cold paths now.
// ---------------------------------------------------------------------------
__device__ __forceinline__ float ldm(const void* p, size_t i, int m) {
    return m ? ((const float*)p)[i]
             : __bfloat162float(((const bf16*)p)[i]);
}
__device__ __forceinline__ void stm(void* p, size_t i, int m, float v) {
    if (m) ((float*)p)[i] = v;
    else   ((bf16*)p)[i] = __float2bfloat16(v);
}

__device__ __forceinline__ void glds16(const bf16* g, bf16* l) {
    __builtin_amdgcn_global_load_lds(
        (const __attribute__((address_space(1))) void*)g,
        (__attribute__((address_space(3))) void*)l, 16, 0, 0);
}

// ---------------------------------------------------------------------------
// Convert (fp32->bf16) or copy (bf16->bf16), 8 elements/thread.
// ---------------------------------------------------------------------------
__global__ __launch_bounds__(256) void cvt_kernel(
    const void* __restrict__ src, bf16* __restrict__ dst, int n8, int m)
{
    int i = blockIdx.x * 256 + threadIdx.x;
    if (i >= n8) return;
    if (m) {
        const f4v* p = (const f4v*)src + (size_t)i * 2;
        f4v a = p[0], b = p[1];
        bf16 t[8];
        #pragma unroll
        for (int e = 0; e < 4; e++) {
            t[e]     = __float2bfloat16(a[e]);
            t[4 + e] = __float2bfloat16(b[e]);
        }
        ((s8v*)dst)[i] = *(s8v*)&t[0];
    } else {
        ((s8v*)dst)[i] = ((const s8v*)src)[i];
    }
}

// ---------------------------------------------------------------------------
// Pure-bf16 MFMA GEMM: C = A (MxK) * Bw (NxK)^T.  128x128 tile, BK=32,
// 256 threads, global_load_lds dwordx4 staging (m97 structure), XCD swizzle.
// cm: 0 -> bf16 C store, 1 -> fp32 C store.
// ---------------------------------------------------------------------------
__global__ __launch_bounds__(256) void gemm_glds_kernel(
    const bf16* __restrict__ A, const bf16* __restrict__ Bw,
    void* __restrict__ C, size_t cOff, int cm, int N, int K)
{
    __shared__ bf16 a_lds[128 * 32];   // linear: glds dest must be unpadded
    __shared__ bf16 b_lds[128 * 32];
    const int t = threadIdx.x;

    // XCD-aware swizzle (nwg % 8 == 0 for all our launches)
    const int nbx = gridDim.x;
    const int id  = blockIdx.y * nbx + blockIdx.x;
    const int cpx = (nbx * (int)gridDim.y) >> 3;
    const int swz = (id & 7) * cpx + (id >> 3);
    const int n0  = (swz % nbx) * 128;
    const int m0  = (swz / nbx) * 128;

    const int w  = t >> 6, ln = t & 63;
    const int wr = w >> 1, wc = w & 1;
    const int fr = ln & 15, kg = ln >> 4;

    // staging: wave w owns tile rows [w*32, w*32+32); lane covers row
    // w*32 + j*16 + ln/4, cols (ln&3)*8 .. +7  (hardware: lds base + lane*16B)
    const int srow = w * 32 + (ln >> 2);
    const int scol = (ln & 3) * 8;
    const bf16* ga = A  + (size_t)(m0 + srow) * K + scol;
    const bf16* gb = Bw + (size_t)(n0 + srow) * K + scol;
    bf16* la = &a_lds[w * 1024];
    bf16* lb = &b_lds[w * 1024];

    f4v acc[4][4];
    #pragma unroll
    for (int i = 0; i < 4; i++)
        #pragma unroll
        for (int j = 0; j < 4; j++)
            #pragma unroll
            for (int r = 0; r < 4; r++) acc[i][j][r] = 0.f;

    for (int k0 = 0; k0 < K; k0 += 32) {
        __syncthreads();
        glds16(ga + k0,          la);
        glds16(ga + k0 + 16 * K, la + 512);
        glds16(gb + k0,          lb);
        glds16(gb + k0 + 16 * K, lb + 512);
        __syncthreads();

        s8v af[4], bfv[4];
        #pragma unroll
        for (int i = 0; i < 4; i++)
            af[i] = *(const s8v*)&a_lds[(wr * 64 + i * 16 + fr) * 32 + kg * 8];
        #pragma unroll
        for (int j = 0; j < 4; j++)
            bfv[j] = *(const s8v*)&b_lds[(wc * 64 + j * 16 + fr) * 32 + kg * 8];
        #pragma unroll
        for (int i = 0; i < 4; i++)
            #pragma unroll
            for (int j = 0; j < 4; j++)
                acc[i][j] = __builtin_amdgcn_mfma_f32_16x16x32_bf16(
                    af[i], bfv[j], acc[i][j], 0, 0, 0);
    }

    #pragma unroll
    for (int i = 0; i < 4; i++)
        #pragma unroll
        for (int j = 0; j < 4; j++)
            #pragma unroll
            for (int r = 0; r < 4; r++) {
                int row = m0 + wr * 64 + i * 16 + kg * 4 + r;
                int col = n0 + wc * 64 + j * 16 + fr;
                stm(C, cOff + (size_t)row * N + col, cm, acc[i][j][r]);
            }
}

// ---------------------------------------------------------------------------
// rotary + RMS-norm, pure-bf16 in-place; optional bf16 copy (kout) and
// external-dtype copy (out2, mode om) for the new_k output.
// ---------------------------------------------------------------------------
__global__ __launch_bounds__(256) void rot_rms_kernel(
    bf16* __restrict__ p, int stride, int ldiv,
    const void* __restrict__ cosb, const void* __restrict__ sinb, int em,
    bf16* __restrict__ kout, void* __restrict__ out2, int om)
{
    const int row  = blockIdx.x * 4 + (threadIdx.x >> 6);
    const int lane = threadIdx.x & 63;
    const int l    = (row / ldiv) % L_;
    bf16* pr = p + (size_t)row * stride;

    float x1 = __bfloat162float(pr[lane]);
    float x2 = __bfloat162float(pr[lane + 64]);
    float c  = ldm(cosb, (size_t)l * 64 + lane, em);
    float s  = ldm(sinb, (size_t)l * 64 + lane, em);
    float y1 =  x1 * c + x2 * s;
    float y2 = -x1 * s + x2 * c;

    float sq = y1 * y1 + y2 * y2;
    #pragma unroll
    for (int off = 32; off > 0; off >>= 1) sq += __shfl_xor(sq, off);
    float rinv = rsqrtf(sq * (1.0f / 128.0f) + 1.1920929e-07f);
    y1 *= rinv; y2 *= rinv;

    pr[lane]      = __float2bfloat16(y1);
    pr[lane + 64] = __float2bfloat16(y2);
    if (kout) {
        kout[(size_t)row * HD_ + lane]      = __float2bfloat16(y1);
        kout[(size_t)row * HD_ + lane + 64] = __float2bfloat16(y2);
    }
    if (out2) {
        stm(out2, (size_t)row * HD_ + lane,      om, y1);
        stm(out2, (size_t)row * HD_ + lane + 64, om, y2);
    }
}

// ---------------------------------------------------------------------------
// V transpose: v (bf16, strided rows) -> vt [B][HD][L] bf16, plus new_v copy
// to out-dtype buffer.
// ---------------------------------------------------------------------------
__global__ __launch_bounds__(256) void transpose_v_kernel(
    const bf16* __restrict__ v, int vstride, int vcol0,
    bf16* __restrict__ vt, void* __restrict__ vout, int om)
{
    const int l0 = blockIdx.x * 32, c0 = blockIdx.y * 32, b = blockIdx.z;
    __shared__ bf16 tile[32][36];
    const int t = threadIdx.x;
    {
        int r = t >> 3, c4 = (t & 7) * 4;
        const bf16* src = v + (size_t)(b * L_ + l0 + r) * vstride + vcol0 + c0 + c4;
        s4v sv = *(const s4v*)src;
        *(s4v*)&tile[r][c4] = sv;
        size_t oidx = (size_t)(b * L_ + l0 + r) * HD_ + c0 + c4;
        if (om) {
            f4v f;
            #pragma unroll
            for (int e = 0; e < 4; e++) f[e] = __bfloat162float(((bf16*)&sv)[e]);
            *(f4v*)((float*)vout + oidx) = f;
        } else {
            *(s4v*)((bf16*)vout + oidx) = sv;
        }
    }
    __syncthreads();
    {
        int c = t >> 3, r4 = (t & 7) * 4;
        bf16 tmp[4];
        #pragma unroll
        for (int e = 0; e < 4; e++) tmp[e] = tile[r4 + e][c];
        *(s4v*)&vt[(size_t)(b * HD_ + c0 + c) * L_ + l0 + r4] = *(s4v*)&tmp[0];
    }
}

// ---------------------------------------------------------------------------
// MFMA causal flash attention, S^T formulation (unchanged this round).
// ---------------------------------------------------------------------------
__global__ __launch_bounds__(256, 3) void attn_kernel(
    const bf16* __restrict__ q,
    const bf16* __restrict__ kbuf,
    const bf16* __restrict__ vt,
    bf16* __restrict__ o)
{
    const int l0 = ((int)gridDim.x - 1 - (int)blockIdx.x) * 128;
    const int h  = blockIdx.y, b = blockIdx.z;
    const int t  = threadIdx.x, w = t >> 6, ln = t & 63;
    const int fr = ln & 15, kg = ln >> 4;

    __shared__ bf16 k_lds[64][136];    // K tile  [key][hd]   (+8 pad)
    __shared__ bf16 vt_lds[128][72];   // V^T tile [hd][key]  (+8 pad)
    __shared__ bf16 p_lds[128][72];    // P tile  [qrow][key] (+8 pad)

    s8v qf[2][4];
    #pragma unroll
    for (int s = 0; s < 2; s++) {
        size_t base = (size_t)(b * L_ + l0 + w * 32 + s * 16 + fr) * D_
                      + h * HD_ + kg * 8;
        #pragma unroll
        for (int kst = 0; kst < 4; kst++)
            qf[s][kst] = *(const s8v*)(q + base + kst * 32);
    }

    float m_i[2] = {-3.0e38f, -3.0e38f};
    float l_i[2] = {0.f, 0.f};
    f4v o_acc[8][2];
    #pragma unroll
    for (int mt = 0; mt < 8; mt++)
        #pragma unroll
        for (int s = 0; s < 2; s++)
            #pragma unroll
            for (int r = 0; r < 4; r++) o_acc[mt][s][r] = 0.f;

    const float scale = 0.08838834764831845f;  // 1/sqrt(128)
    const int qmax_w = l0 + w * 32 + 31;
    const int kend   = l0 + 128;

    for (int kb = 0; kb < kend; kb += 64) {
        __syncthreads();
        {
            int r = t >> 2, c0 = (t & 3) * 32;
            const s8v* src = (const s8v*)(kbuf + (size_t)(b * L_ + kb + r) * HD_ + c0);
            #pragma unroll
            for (int s = 0; s < 4; s++)
                *(s8v*)&k_lds[r][c0 + s * 8] = src[s];
        }
        {
            int r = t >> 1, c0 = (t & 1) * 32;
            const s8v* src = (const s8v*)(vt + (size_t)(b * HD_ + r) * L_ + kb + c0);
            #pragma unroll
            for (int s = 0; s < 4; s++)
                *(s8v*)&vt_lds[r][c0 + s * 8] = src[s];
        }
        __syncthreads();

        if (kb <= qmax_w) {
            f4v sacc[4][2];
            #pragma unroll
            for (int jm = 0; jm < 4; jm++)
                #pragma unroll
                for (int s = 0; s < 2; s++)
                    #pragma unroll
                    for (int r = 0; r < 4; r++) sacc[jm][s][r] = 0.f;
            #pragma unroll
            for (int kst = 0; kst < 4; kst++) {
                #pragma unroll
                for (int jm = 0; jm < 4; jm++) {
                    s8v af = *(const s8v*)&k_lds[jm * 16 + fr][kst * 32 + kg * 8];
                    #pragma unroll
                    for (int s = 0; s < 2; s++)
                        sacc[jm][s] = __builtin_amdgcn_mfma_f32_16x16x32_bf16(
                            af, qf[s][kst], sacc[jm][s], 0, 0, 0);
                }
            }

            #pragma unroll
            for (int s = 0; s < 2; s++) {
                const int qrow = l0 + w * 32 + s * 16 + fr;
                float sv[4][4];
                float mx = -1.0e30f;
                #pragma unroll
                for (int jm = 0; jm < 4; jm++)
                    #pragma unroll
                    for (int r = 0; r < 4; r++) {
                        int key = kb + jm * 16 + kg * 4 + r;
                        float v = sacc[jm][s][r] * scale;
                        v = (key <= qrow) ? v : -1.0e30f;
                        sv[jm][r] = v;
                        mx = fmaxf(mx, v);
                    }
                mx = fmaxf(mx, __shfl_xor(mx, 16));
                mx = fmaxf(mx, __shfl_xor(mx, 32));
                float mn = fmaxf(m_i[s], mx);
                float alpha = __expf(m_i[s] - mn);
                m_i[s] = mn;
                float rsum = 0.f;
                #pragma unroll
                for (int jm = 0; jm < 4; jm++) {
                    bf16 pb[4];
                    #pragma unroll
                    for (int r = 0; r < 4; r++) {
                        float pe = __expf(sv[jm][r] - mn);
                        rsum += pe;
                        pb[r] = __float2bfloat16(pe);
                    }
                    *(s4v*)&p_lds[w * 32 + s * 16 + fr][jm * 16 + kg * 4] =
                        *(s4v*)&pb[0];
                }
                rsum += __shfl_xor(rsum, 16);
                rsum += __shfl_xor(rsum, 32);
                l_i[s] = l_i[s] * alpha + rsum;
                #pragma unroll
                for (int mt = 0; mt < 8; mt++)
                    #pragma unroll
                    for (int r = 0; r < 4; r++) o_acc[mt][s][r] *= alpha;
            }

            #pragma unroll
            for (int ks = 0; ks < 2; ks++) {
                s8v pf[2];
                #pragma unroll
                for (int s = 0; s < 2; s++)
                    pf[s] = *(const s8v*)&p_lds[w * 32 + s * 16 + fr][ks * 32 + kg * 8];
                #pragma unroll
                for (int mt = 0; mt < 8; mt++) {
                    s8v vf = *(const s8v*)&vt_lds[mt * 16 + fr][ks * 32 + kg * 8];
                    #pragma unroll
                    for (int s = 0; s < 2; s++)
                        o_acc[mt][s] = __builtin_amdgcn_mfma_f32_16x16x32_bf16(
                            vf, pf[s], o_acc[mt][s], 0, 0, 0);
                }
            }
        }
    }

    #pragma unroll
    for (int s = 0; s < 2; s++) {
        float rl = 1.f / l_i[s];
        size_t base = (size_t)(b * L_ + l0 + w * 32 + s * 16 + fr) * D_
                      + h * HD_ + kg * 4;
        #pragma unroll
        for (int mt = 0; mt < 8; mt++) {
            bf16 ob[4];
            #pragma unroll
            for (int r = 0; r < 4; r++)
                ob[r] = __float2bfloat16(o_acc[mt][s][r] * rl);
            *(s4v*)(o + base + mt * 16) = *(s4v*)&ob[0];
        }
    }
}

// ---------------------------------------------------------------------------
extern "C" void kernel_launch(void* const* d_in, const int* in_sizes, int n_in,
                              void* d_out, int out_size, void* d_ws, size_t ws_size,
                              hipStream_t stream)
{
    const void* x    = d_in[0];
    const void* cosb = d_in[1];
    const void* sinb = d_in[2];
    const void* Wq   = d_in[3];
    const void* Wk   = d_in[4];
    const void* Wv   = d_in[5];
    const void* Wo   = d_in[6];

    const size_t NX   = (size_t)B_ * L_ * D_;     // 16,777,216
    const size_t NW   = (size_t)D_ * D_;          //  4,194,304
    const size_t NWK  = (size_t)HD_ * D_;         //    262,144
    const size_t NKV  = (size_t)B_ * L_ * HD_;    //  1,048,576
    const size_t NOUT = NX + 2 * NKV;             // 18,874,368

    // host-side dtype dispatch (byte sizes); default fp32
    const int xm  = (in_sizes[0] == (int)(NX * 2))  ? 0 : 1;
    const int em  = (in_sizes[1] == (int)((size_t)L_ * 64 * 2)) ? 0 : 1;
    const int wm  = (in_sizes[3] == (int)(NW * 2))  ? 0 : 1;
    const int wkm = (in_sizes[4] == (int)(NWK * 2)) ? 0 : 1;
    const int om  = (out_size    == (int)(NOUT * 2)) ? 0 : 1;

    // workspace layout (~43 MiB):
    //   qbuf  [M][2048] bf16      32 MiB
    //   kvbuf [M][256]  bf16       4 MiB   \
    //   kbuf  [M][128]  bf16       2 MiB    } wwb (8 MiB, Wq then Wo) aliases
    //   vtbuf [B][HD][L] bf16      2 MiB   /  these three (stream-ordered)
    //   wkvb  [256][2048] bf16     1 MiB
    bf16* qbuf  = (bf16*)d_ws;
    bf16* kvbuf = qbuf  + NX;
    bf16* kbuf  = kvbuf + (size_t)B_ * L_ * 256;
    bf16* vtbuf = kbuf  + NKV;
    bf16* wkvb  = vtbuf + NKV;
    bf16* wwb   = kvbuf;   // 8 MiB scratch spanning kvbuf+kbuf+vtbuf

    // x bf16 copy lives in d_out scratch (dead before final GEMM writes it)
    const bf16* xb;
    if (xm) {
        cvt_kernel<<<(int)(NX / 8 / 256), 256, 0, stream>>>(x, (bf16*)d_out, (int)(NX / 8), 1);
        xb = (const bf16*)d_out;
    } else {
        xb = (const bf16*)x;
    }

    const bf16* wq;
    if (wm) {
        cvt_kernel<<<(int)(NW / 8 / 256), 256, 0, stream>>>(Wq, wwb, (int)(NW / 8), 1);
        wq = wwb;
    } else {
        wq = (const bf16*)Wq;
    }
    cvt_kernel<<<(int)(NWK / 8 / 256), 256, 0, stream>>>(Wk, wkvb,       (int)(NWK / 8), wkm);
    cvt_kernel<<<(int)(NWK / 8 / 256), 256, 0, stream>>>(Wv, wkvb + NWK, (int)(NWK / 8), wkm);

    // q = x @ Wq^T  (bf16 out into qbuf)
    gemm_glds_kernel<<<dim3(D_ / 128, (B_ * L_) / 128), 256, 0, stream>>>(
        xb, wq, qbuf, 0, 0, D_, D_);
    // [k|v] = x @ [Wk;Wv]^T  (bf16 out into kvbuf, N=256)
    gemm_glds_kernel<<<dim3(256 / 128, (B_ * L_) / 128), 256, 0, stream>>>(
        xb, wkvb, kvbuf, 0, 0, 256, D_);

    // rotary + rms
    rot_rms_kernel<<<(B_ * L_ * H_) / 4, 256, 0, stream>>>(
        qbuf, HD_, H_, cosb, sinb, em, nullptr, nullptr, 0);
    char* d_out_b = (char*)d_out;
    void* kout2 = d_out_b + NX * (om ? 4 : 2);
    rot_rms_kernel<<<(B_ * L_) / 4, 256, 0, stream>>>(
        kvbuf, 256, 1, cosb, sinb, em, kbuf, kout2, om);

    // v: transpose for attention + new_v copy to output
    void* vout2 = d_out_b + (NX + NKV) * (om ? 4 : 2);
    transpose_v_kernel<<<dim3(L_ / 32, HD_ / 32, B_), 256, 0, stream>>>(
        kvbuf, 256, 128, vtbuf, vout2, om);

    // attention (in-place into qbuf)
    attn_kernel<<<dim3(L_ / 128, H_, B_), 256, 0, stream>>>(
        qbuf, kbuf, vtbuf, qbuf);

    // Wo conversion reuses wwb (kvbuf/kbuf/vtbuf all dead after attn)
    const bf16* wo;
    if (wm) {
        cvt_kernel<<<(int)(NW / 8 / 256), 256, 0, stream>>>(Wo, wwb, (int)(NW / 8), 1);
        wo = wwb;
    } else {
        wo = (const bf16*)Wo;
    }
    // out = attn @ Wo^T  (out-dtype store into d_out)
    gemm_glds_kernel<<<dim3(D_ / 128, (B_ * L_) / 128), 256, 0, stream>>>(
        qbuf, wo, d_out, 0, om, D_, D_);
}